// Round 1
// baseline (227.133 us; speedup 1.0000x reference)
//
#include <hip/hip_runtime.h>

// SMPL body model forward.
// R14: k_gl stage-2 restructure. The smT LDS round-trip + 32 barriers/block
// were the serialization (MfmaUtil 5%, VALUBusy 8%, HBM 10%, occ 16% -> pure
// latency). Operand-swapped T-MFMA (mfma(an16,w16) instead of mfma(w16,an16))
// puts T row q for vertex w*16+m directly in lane (m,q)'s f32x4 -- the apply
// is inline per-lane math. smT deleted (LDS 49K->35.5K, 3->4 blocks/CU),
// stage 2 is barrier-free. Posed verts repacked sm[n][v(65 pad)][4] fp16 so
// apply needs one conflict-free ds_read_b64 instead of 3 ds_read_u16.

constexpr int N   = 512;
constexpr int V   = 6890;
constexpr int V3  = V * 3;        // 20670
constexpr int NJ  = 24;
constexpr int NB  = 10;
constexpr int NP  = 207;
constexpr int NK  = 95;
constexpr int KP  = 224;          // padded K for pose GEMM
constexpr int VP2 = 6912;         // V padded (108*64)

// workspace layout (float offsets)
constexpr size_t SCALE_OFF = (size_t)N * V3;                  // N
constexpr size_t SJ_OFF    = SCALE_OFF + N;                   // NB*72
constexpr size_t JT_OFF    = SJ_OFF + (size_t)NB * 72;        // 72
constexpr size_t J_OFF     = JT_OFF + 72;
constexpr size_t A_OFF     = J_OFF + (size_t)N * 72;
constexpr size_t BF_OFF    = A_OFF + (size_t)N * 288;         // bf16/fp16 region
// region (ushort offsets)
constexpr size_t APF_U     = 0;                               // apf_sw [N/16][7][64][8] bf16
constexpr int    BP_COLS   = 20736;                           // 108*192 col pad
constexpr size_t BP_U      = (size_t)N * KP;                  // bp_sw [1296][7][64][8] bf16
constexpr size_t RB_U      = BP_U + (size_t)BP_COLS * KP;     // reg fp16 [96][VP2]
constexpr size_t VB_U      = RB_U + (size_t)96 * VP2;         // verts fp16 [N][3][VP2]
constexpr size_t BF_END_U  = VB_U + (size_t)N * 3 * VP2;
constexpr size_t WT_OFF    = BF_OFF + (BF_END_U + 1) / 2;     // w16 fp16 [VP2][32]
constexpr size_t AN_OFF    = WT_OFF + (size_t)VP2 * 32 / 2;   // an16 fp16 [N][16][32]

// k_static section block counts
constexpr int NB_REGBF = (96 * VP2) / 256;   // 2592
constexpr int NB_BT    = BP_COLS / 64;       // 324
constexpr int NB_WT    = VP2 / 256;          // 27
constexpr int NB_PRE   = 72;
constexpr int NB_STATIC = NB_REGBF + NB_BT + NB_WT + NB_PRE;

typedef short s16x8 __attribute__((ext_vector_type(8)));
typedef _Float16 h16x8 __attribute__((ext_vector_type(8)));
typedef _Float16 h16x4 __attribute__((ext_vector_type(4)));
typedef float f32x4 __attribute__((ext_vector_type(4)));

__device__ inline unsigned short f2bf(float f) {
    unsigned u = __float_as_uint(f);
    u += 0x7fffu + ((u >> 16) & 1u);   // round-to-nearest-even
    return (unsigned short)(u >> 16);
}

// ---------------------------------------------------------------------------
// k_static: sectioned batch-independent prep (regbf | bt | wt | pre).
__global__ __launch_bounds__(256) void k_static(const float* __restrict__ pdirs,
                                                const float* __restrict__ sd,
                                                const float* __restrict__ jreg,
                                                const float* __restrict__ vt,
                                                const float* __restrict__ lbsw,
                                                const float* __restrict__ b25,
                                                const float* __restrict__ face,
                                                unsigned short* __restrict__ bp,
                                                _Float16* __restrict__ rb,
                                                _Float16* __restrict__ w16,
                                                float* __restrict__ ws) {
    __shared__ unsigned short smem[KP * 64];     // 28 KB, reused per section
    int b = blockIdx.x;
    int tid = threadIdx.x;

    if (b < NB_REGBF) {
        int t = b * 256 + tid;
        int k = t / VP2, v = t - k * VP2;
        float val = 0.f;
        if (v < V && k < NK)
            val = (k < 25) ? b25[(size_t)k * V + v] : face[(size_t)(k - 25) * V + v];
        rb[t] = (_Float16)val;
        return;
    }
    b -= NB_REGBF;
    if (b < NB_BT) {
        // stage [k][cl] then emit FRAGMENT layout bp[(ctg*7+kk)*64+lane][8]
        int c0 = b * 64;
#pragma unroll 4
        for (int i = 0; i < 56; ++i) {
            int e = tid + 256 * i;
            int k = e >> 6, cl = e & 63;
            int col = c0 + cl;
            float v = 0.f;
            if (col < V3) {
                if (k < NP) v = pdirs[(size_t)k * V3 + col];
                else if (k < NP + NB) v = sd[(size_t)(k - NP) * V3 + col];
            }
            smem[k * 64 + cl] = f2bf(v);
        }
        __syncthreads();
        for (int i = 0; i < 7; ++i) {
            int u = tid + 256 * i;                // 0..1791
            int ct_loc = u / 448;
            int rem = u - ct_loc * 448;
            int kk = rem >> 6, lane = rem & 63;
            int m = lane & 15, q = lane >> 4;
            s16x8 r;
#pragma unroll
            for (int j = 0; j < 8; ++j)
                r[j] = (short)smem[(kk * 32 + q * 8 + j) * 64 + ct_loc * 16 + m];
            size_t ctg = (size_t)(c0 >> 4) + ct_loc;
            *reinterpret_cast<s16x8*>(&bp[((ctg * 7 + kk) * 64 + lane) * 8]) = r;
        }
        return;
    }
    b -= NB_BT;
    if (b < NB_WT) {
        // w16[v][k=j] fp16, A-operand layout for the T-MFMA
        float* t = reinterpret_cast<float*>(smem);
        int v0 = b * 256;
        for (int e = tid; e < 256 * 24; e += 256) {
            int g = v0 * 24 + e;
            float val = (g < V * NJ) ? lbsw[g] : 0.f;
            int vv = e / 24, j = e - vv * 24;
            t[vv * 25 + j] = val;
        }
        __syncthreads();
        _Float16* dst = w16 + (size_t)(v0 + tid) * 32;
#pragma unroll
        for (int j = 0; j < 32; ++j)
            dst[j] = (j < NJ) ? (_Float16)t[tid * 25 + j] : (_Float16)0.f;
        return;
    }
    b -= NB_WT;
    // pre: SJ / Jt, block per jc, shuffle reduce
    int jc = b;
    int j = jc / 3, c = jc % 3;
    float acc[NB + 1];
#pragma unroll
    for (int t = 0; t <= NB; ++t) acc[t] = 0.f;
    for (int v = tid; v < V; v += 256) {
        float w = jreg[(size_t)j * V + v];
        int col = v * 3 + c;
#pragma unroll
        for (int k = 0; k < NB; ++k) acc[k] += w * sd[(size_t)k * V3 + col];
        acc[NB] += w * vt[col];
    }
    float* red = reinterpret_cast<float*>(smem);
    int lane = tid & 63, w64 = tid >> 6;
#pragma unroll
    for (int t = 0; t <= NB; ++t) {
        float a = acc[t];
#pragma unroll
        for (int s = 1; s < 64; s <<= 1) a += __shfl_xor(a, s, 64);
        if (lane == 0) red[w64 * 16 + t] = a;
    }
    __syncthreads();
    if (tid <= NB) {
        float s = red[tid] + red[16 + tid] + red[32 + tid] + red[48 + tid];
        if (tid < NB) ws[SJ_OFF + (size_t)tid * 72 + jc] = s;
        else          ws[JT_OFF + jc] = s;
    }
}

// ---------------------------------------------------------------------------
// k_head: scale + J + apf(fragment layout) + FK + an16. One wave per n.
__global__ __launch_bounds__(64) void k_head(const float* __restrict__ pose,
                                             const float* __restrict__ betas,
                                             const float* __restrict__ vt,
                                             const float* __restrict__ sd,
                                             float* __restrict__ ws,
                                             unsigned short* __restrict__ apf,
                                             _Float16* __restrict__ an16) {
    int n = blockIdx.x;
    int tid = threadIdx.x;
    __shared__ float sval[4];
    __shared__ float Jl[NJ * 3];
    __shared__ float G[NJ * 12];
    __shared__ unsigned short pfsh[KP];

    const int idx4[4] = {2802 * 3 + 1, 6262 * 3 + 1, 2237 * 3 + 1, 6728 * 3 + 1};
    if (tid < 4) {
        float a = vt[idx4[tid]];
#pragma unroll
        for (int k = 0; k < NB; ++k)
            a += betas[n * NB + k] * sd[(size_t)k * V3 + idx4[tid]];
        sval[tid] = a;
    }
    __syncthreads();
    float scale = 1.66f / (sval[0] + sval[1] - sval[2] - sval[3]);
    if (tid == 0) ws[SCALE_OFF + n] = scale;

    for (int k = tid; k < KP; k += 64) {
        float v = 0.f;
        if (k < NP) {
            v = pose[(size_t)n * 216 + 9 + k];
            int km = k % 9;
            if (km == 0 || km == 4 || km == 8) v -= 1.f;
        } else if (k < NP + NB) {
            v = scale * betas[n * NB + (k - NP)];
        }
        pfsh[k] = f2bf(v);
    }
    for (int e = tid; e < 72; e += 64) {
        float a = ws[JT_OFF + e];
#pragma unroll
        for (int k = 0; k < NB; ++k)
            a += betas[n * NB + k] * ws[SJ_OFF + (size_t)k * 72 + e];
        Jl[e] = scale * a;
    }
    __syncthreads();
    // apf fragment layout: [(n/16)*7+kk][lane=q*16+(n&15)][8]
    if (tid < 28) {
        int kk = tid >> 2, q = tid & 3;
        s16x8 r;
#pragma unroll
        for (int j = 0; j < 8; ++j) r[j] = (short)pfsh[kk * 32 + q * 8 + j];
        size_t off = ((size_t)(n >> 4) * 7 + kk) * 64 + q * 16 + (n & 15);
        *reinterpret_cast<s16x8*>(&apf[off * 8]) = r;
    }

    const int par[NJ] = {0,0,0,0,1,2,3,4,5,6,7,8,9,9,9,12,13,14,16,17,18,19,20,21};
    if (tid < 12) {
        int r = tid >> 2, c = tid & 3;
        G[tid] = (c < 3) ? pose[(size_t)n * 216 + r * 3 + c] : Jl[r];
    }
    __syncthreads();
    for (int i = 1; i < NJ; ++i) {
        int p = par[i];
        if (tid < 12) {
            int r = tid >> 2, c = tid & 3;
            const float* gp = &G[p * 12 + r * 4];
            float v;
            if (c < 3) {
                const float* Ri = pose + (size_t)n * 216 + i * 9;
                v = gp[0] * Ri[0 * 3 + c] + gp[1] * Ri[1 * 3 + c] + gp[2] * Ri[2 * 3 + c];
            } else {
                float t0 = Jl[i * 3 + 0] - Jl[p * 3 + 0];
                float t1 = Jl[i * 3 + 1] - Jl[p * 3 + 1];
                float t2 = Jl[i * 3 + 2] - Jl[p * 3 + 2];
                v = gp[0] * t0 + gp[1] * t1 + gp[2] * t2 + gp[3];
            }
            G[i * 12 + tid] = v;
        }
        __syncthreads();
    }
    // an16[n][col(16)][k=j(32)]
    for (int e = tid; e < 512; e += 64) {
        int col = e >> 5, j = e & 31;
        float v = 0.f;
        if (col < 12 && j < NJ) {
            int r = col >> 2, c = col & 3;
            if (c < 3) v = G[j * 12 + r * 4 + c];
            else {
                const float* g = &G[j * 12 + r * 4];
                v = g[3] - (g[0] * Jl[j * 3 + 0] + g[1] * Jl[j * 3 + 1] + g[2] * Jl[j * 3 + 2]);
            }
        }
        an16[(size_t)n * 512 + e] = (_Float16)v;
    }
}

// ---------------------------------------------------------------------------
// k_gl: fused pose-GEMM + LBS. R14: barrier-free stage 2 via operand-swapped
// T-MFMA. mfma(an16_frag, w16_frag): D[row=an16col, col=v] -> lane (m,q)
// holds at[0..3] = T[q][0..3] for vertex w*16+m (an16 col encoding r*4+c).
// Apply is inline; no smT, no stage-2 barriers.
__global__ __launch_bounds__(256) void k_gl(const unsigned short* __restrict__ apf,
                                            const unsigned short* __restrict__ bp,
                                            const float* __restrict__ vt,
                                            const float* __restrict__ ws,
                                            const _Float16* __restrict__ w16,
                                            const _Float16* __restrict__ an16,
                                            const float* __restrict__ trans,
                                            _Float16* __restrict__ vb) {
    int tid = threadIdx.x;
    int lane = tid & 63, w = tid >> 6;
    int m = lane & 15, q = lane >> 4;
    int cb = blockIdx.x;                 // 0..107  (64-v tile)
    int nb = blockIdx.y;                 // 0..7    (64-n tile)
    int nt = nb * 4 + w;

    // posed verts, packed per-vertex: [n][v(65 pad)][c(4)] fp16 = 33.3 KB.
    // stride per n = 520 B (65*8): 8B-aligned, breaks pow2 banking.
    __shared__ __align__(16) _Float16 sm[64][65][4];
    __shared__ float svt[192];
    __shared__ float ssc[64];
    __shared__ float strans[192];
    if (tid < 192) {
        int col = cb * 192 + tid;
        svt[tid] = (col < V3) ? vt[col] : 0.f;
        strans[tid] = trans[nb * 192 + tid];
    }
    if (tid < 64) ssc[tid] = ws[SCALE_OFF + nb * 64 + tid];

    // ---- stage 1: pose GEMM
    const unsigned short* abase = apf + (size_t)nt * 7 * 512 + lane * 8;
    const unsigned short* bbase = bp + (size_t)cb * 12 * 7 * 512 + lane * 8;

    f32x4 acc[12];
#pragma unroll
    for (int ct = 0; ct < 12; ++ct) acc[ct] = (f32x4){0.f, 0.f, 0.f, 0.f};

#pragma unroll
    for (int kk = 0; kk < 7; ++kk) {
        s16x8 a = *reinterpret_cast<const s16x8*>(abase + kk * 512);
#pragma unroll
        for (int ct = 0; ct < 12; ++ct) {
            s16x8 bfr = *reinterpret_cast<const s16x8*>(bbase + (ct * 7 + kk) * 512);
            acc[ct] = __builtin_amdgcn_mfma_f32_16x16x32_bf16(a, bfr, acc[ct], 0, 0, 0);
        }
    }
    __syncthreads();          // svt/ssc/strans ready
#pragma unroll
    for (int ct = 0; ct < 12; ++ct) {
        int col_loc = ct * 16 + m;
        int v_loc = col_loc / 3;
        int c = col_loc - 3 * v_loc;
        float vtc = svt[col_loc];
#pragma unroll
        for (int r = 0; r < 4; ++r) {
            int n_loc = w * 16 + q * 4 + r;
            sm[n_loc][v_loc][c] = (_Float16)(acc[ct][r] + ssc[n_loc] * vtc);
        }
    }

    // ---- stage 2: LBS, barrier-free
    h16x8 wf = *reinterpret_cast<const h16x8*>(
        &w16[(size_t)(cb * 64 + w * 16 + m) * 32 + q * 8]);
    __syncthreads();                          // sm complete

    int vl = w * 16 + m;
    const _Float16* anb = an16 + (size_t)nb * 64 * 512 + m * 32 + q * 8;
    _Float16* vbase = vb + (size_t)nb * 64 * 3 * VP2 + (size_t)q * VP2
                      + (size_t)cb * 64 + vl;
#pragma unroll 4
    for (int nl = 0; nl < 64; ++nl) {
        h16x8 bf = *reinterpret_cast<const h16x8*>(anb + (size_t)nl * 512);
        f32x4 at = {0.f, 0.f, 0.f, 0.f};
        at = __builtin_amdgcn_mfma_f32_16x16x32_f16(bf, wf, at, 0, 0, 0);
        h16x4 p = *reinterpret_cast<const h16x4*>(&sm[nl][vl][0]);
        if (q < 3) {
            float r = at[0] * (float)p[0] + at[1] * (float)p[1]
                    + at[2] * (float)p[2] + at[3] + strans[nl * 3 + q];
            vbase[(size_t)nl * 3 * VP2] = (_Float16)r;
        }
    }
}

// ---------------------------------------------------------------------------
// k_regm v4: grid (96 nc-tiles x 6 v-splits) = 576 blocks (~9 waves/CU).
// Each wave: 9 K-steps. LDS combine across 4 waves, atomicAdd partials.
__global__ __launch_bounds__(256) void k_regm(const _Float16* __restrict__ rb,
                                              const _Float16* __restrict__ vb,
                                              float* __restrict__ out) {
    int tid = threadIdx.x;
    int lane = tid & 63, w = tid >> 6;
    int m = lane & 15, q = lane >> 4;
    int nct = blockIdx.x;                    // 0..95
    int split = blockIdx.y;                  // 0..5

    const _Float16* brow = vb + (size_t)(nct * 16 + m) * VP2 + q * 8;
    const _Float16* abase = rb + (size_t)m * VP2 + q * 8;
    int vstart = (split * 4 + w) * 288;      // 9 steps of 32 per wave

    f32x4 acc[6];
#pragma unroll
    for (int kt = 0; kt < 6; ++kt) acc[kt] = (f32x4){0.f, 0.f, 0.f, 0.f};

#pragma unroll
    for (int s = 0; s < 9; ++s) {
        int off = vstart + s * 32;
        h16x8 b = *reinterpret_cast<const h16x8*>(brow + off);
#pragma unroll
        for (int kt = 0; kt < 6; ++kt) {
            h16x8 a = *reinterpret_cast<const h16x8*>(abase + (size_t)kt * 16 * VP2 + off);
            acc[kt] = __builtin_amdgcn_mfma_f32_16x16x32_f16(a, b, acc[kt], 0, 0, 0);
        }
    }
    __shared__ float sm[4][6][256];          // 24 KB
#pragma unroll
    for (int kt = 0; kt < 6; ++kt)
#pragma unroll
        for (int r = 0; r < 4; ++r)
            sm[w][kt][(q * 4 + r) * 16 + m] = acc[kt][r];
    __syncthreads();
    for (int e = tid; e < 6 * 256; e += 256) {
        int kt = e >> 8, i = e & 255;
        float s = sm[0][kt][i] + sm[1][kt][i] + sm[2][kt][i] + sm[3][kt][i];
        int k = kt * 16 + (i >> 4);
        int nc = nct * 16 + (i & 15);
        if (k < NK) {
            int n = nc / 3, c = nc - n * 3;
            atomicAdd(&out[(size_t)n * (NK * 3) + k * 3 + c], s);
        }
    }
}

// ---------------------------------------------------------------------------
extern "C" void kernel_launch(void* const* d_in, const int* in_sizes, int n_in,
                              void* d_out, int out_size, void* d_ws, size_t ws_size,
                              hipStream_t stream) {
    const float* pose  = (const float*)d_in[0];
    const float* betas = (const float*)d_in[1];
    const float* trans = (const float*)d_in[2];
    const float* vt    = (const float*)d_in[3];
    const float* sd    = (const float*)d_in[4];
    const float* jreg  = (const float*)d_in[5];
    const float* pdirs = (const float*)d_in[6];
    const float* lbsw  = (const float*)d_in[7];
    const float* b25   = (const float*)d_in[8];
    const float* face  = (const float*)d_in[9];
    float* ws  = (float*)d_ws;
    float* out = (float*)d_out;
    unsigned short* bf  = (unsigned short*)(ws + BF_OFF);
    unsigned short* apf = bf + APF_U;
    unsigned short* bp  = bf + BP_U;
    _Float16* rb  = (_Float16*)(bf + RB_U);
    _Float16* vb  = (_Float16*)(bf + VB_U);
    _Float16* w16 = (_Float16*)(ws + WT_OFF);
    _Float16* an16 = (_Float16*)(ws + AN_OFF);

    hipMemsetAsync(d_out, 0, (size_t)out_size * sizeof(float), stream);

    k_static<<<NB_STATIC, 256, 0, stream>>>(pdirs, sd, jreg, vt, lbsw, b25, face,
                                            bp, rb, w16, ws);
    k_head  <<<N, 64, 0, stream>>>(pose, betas, vt, sd, ws, apf, an16);
    k_gl    <<<dim3(108, 8), 256, 0, stream>>>(apf, bp, vt, ws, w16, an16, trans, vb);
    k_regm  <<<dim3(96, 6), 256, 0, stream>>>(rb, vb, out);
}

// Round 2
// 201.244 us; speedup vs baseline: 1.1286x; 1.1286x over previous
//
#include <hip/hip_runtime.h>

// SMPL body model forward.
// R15: k_gl stage-2 re-partition. R14 (84us, worse than R13's 55.8) had each
// wave iterate all 64 n's for 16 vertices: 64 serial {1KB global an16 load ->
// 1 MFMA -> scalar store} chains, with all 4 waves loading IDENTICAL an16
// rows. Fix: wave w owns n-slice w*16..w*16+15 (exactly the rows its stage-1
// MFMAs produced into sm) x all 64 vertices via 4 register-resident w16
// fragments. 4x fewer an16 loads (and disjoint across waves), 4-way MFMA ILP
// per load, uniform-row ds_read_b64 (conflict-free), still only 2 barriers.

constexpr int N   = 512;
constexpr int V   = 6890;
constexpr int V3  = V * 3;        // 20670
constexpr int NJ  = 24;
constexpr int NB  = 10;
constexpr int NP  = 207;
constexpr int NK  = 95;
constexpr int KP  = 224;          // padded K for pose GEMM
constexpr int VP2 = 6912;         // V padded (108*64)

// workspace layout (float offsets)
constexpr size_t SCALE_OFF = (size_t)N * V3;                  // N
constexpr size_t SJ_OFF    = SCALE_OFF + N;                   // NB*72
constexpr size_t JT_OFF    = SJ_OFF + (size_t)NB * 72;        // 72
constexpr size_t J_OFF     = JT_OFF + 72;
constexpr size_t A_OFF     = J_OFF + (size_t)N * 72;
constexpr size_t BF_OFF    = A_OFF + (size_t)N * 288;         // bf16/fp16 region
// region (ushort offsets)
constexpr size_t APF_U     = 0;                               // apf_sw [N/16][7][64][8] bf16
constexpr int    BP_COLS   = 20736;                           // 108*192 col pad
constexpr size_t BP_U      = (size_t)N * KP;                  // bp_sw [1296][7][64][8] bf16
constexpr size_t RB_U      = BP_U + (size_t)BP_COLS * KP;     // reg fp16 [96][VP2]
constexpr size_t VB_U      = RB_U + (size_t)96 * VP2;         // verts fp16 [N][3][VP2]
constexpr size_t BF_END_U  = VB_U + (size_t)N * 3 * VP2;
constexpr size_t WT_OFF    = BF_OFF + (BF_END_U + 1) / 2;     // w16 fp16 [VP2][32]
constexpr size_t AN_OFF    = WT_OFF + (size_t)VP2 * 32 / 2;   // an16 fp16 [N][16][32]

// k_static section block counts
constexpr int NB_REGBF = (96 * VP2) / 256;   // 2592
constexpr int NB_BT    = BP_COLS / 64;       // 324
constexpr int NB_WT    = VP2 / 256;          // 27
constexpr int NB_PRE   = 72;
constexpr int NB_STATIC = NB_REGBF + NB_BT + NB_WT + NB_PRE;

typedef short s16x8 __attribute__((ext_vector_type(8)));
typedef _Float16 h16x8 __attribute__((ext_vector_type(8)));
typedef _Float16 h16x4 __attribute__((ext_vector_type(4)));
typedef float f32x4 __attribute__((ext_vector_type(4)));

__device__ inline unsigned short f2bf(float f) {
    unsigned u = __float_as_uint(f);
    u += 0x7fffu + ((u >> 16) & 1u);   // round-to-nearest-even
    return (unsigned short)(u >> 16);
}

// ---------------------------------------------------------------------------
// k_static: sectioned batch-independent prep (regbf | bt | wt | pre).
__global__ __launch_bounds__(256) void k_static(const float* __restrict__ pdirs,
                                                const float* __restrict__ sd,
                                                const float* __restrict__ jreg,
                                                const float* __restrict__ vt,
                                                const float* __restrict__ lbsw,
                                                const float* __restrict__ b25,
                                                const float* __restrict__ face,
                                                unsigned short* __restrict__ bp,
                                                _Float16* __restrict__ rb,
                                                _Float16* __restrict__ w16,
                                                float* __restrict__ ws) {
    __shared__ unsigned short smem[KP * 64];     // 28 KB, reused per section
    int b = blockIdx.x;
    int tid = threadIdx.x;

    if (b < NB_REGBF) {
        int t = b * 256 + tid;
        int k = t / VP2, v = t - k * VP2;
        float val = 0.f;
        if (v < V && k < NK)
            val = (k < 25) ? b25[(size_t)k * V + v] : face[(size_t)(k - 25) * V + v];
        rb[t] = (_Float16)val;
        return;
    }
    b -= NB_REGBF;
    if (b < NB_BT) {
        // stage [k][cl] then emit FRAGMENT layout bp[(ctg*7+kk)*64+lane][8]
        int c0 = b * 64;
#pragma unroll 4
        for (int i = 0; i < 56; ++i) {
            int e = tid + 256 * i;
            int k = e >> 6, cl = e & 63;
            int col = c0 + cl;
            float v = 0.f;
            if (col < V3) {
                if (k < NP) v = pdirs[(size_t)k * V3 + col];
                else if (k < NP + NB) v = sd[(size_t)(k - NP) * V3 + col];
            }
            smem[k * 64 + cl] = f2bf(v);
        }
        __syncthreads();
        for (int i = 0; i < 7; ++i) {
            int u = tid + 256 * i;                // 0..1791
            int ct_loc = u / 448;
            int rem = u - ct_loc * 448;
            int kk = rem >> 6, lane = rem & 63;
            int m = lane & 15, q = lane >> 4;
            s16x8 r;
#pragma unroll
            for (int j = 0; j < 8; ++j)
                r[j] = (short)smem[(kk * 32 + q * 8 + j) * 64 + ct_loc * 16 + m];
            size_t ctg = (size_t)(c0 >> 4) + ct_loc;
            *reinterpret_cast<s16x8*>(&bp[((ctg * 7 + kk) * 64 + lane) * 8]) = r;
        }
        return;
    }
    b -= NB_BT;
    if (b < NB_WT) {
        // w16[v][k=j] fp16, A-operand layout for the T-MFMA
        float* t = reinterpret_cast<float*>(smem);
        int v0 = b * 256;
        for (int e = tid; e < 256 * 24; e += 256) {
            int g = v0 * 24 + e;
            float val = (g < V * NJ) ? lbsw[g] : 0.f;
            int vv = e / 24, j = e - vv * 24;
            t[vv * 25 + j] = val;
        }
        __syncthreads();
        _Float16* dst = w16 + (size_t)(v0 + tid) * 32;
#pragma unroll
        for (int j = 0; j < 32; ++j)
            dst[j] = (j < NJ) ? (_Float16)t[tid * 25 + j] : (_Float16)0.f;
        return;
    }
    b -= NB_WT;
    // pre: SJ / Jt, block per jc, shuffle reduce
    int jc = b;
    int j = jc / 3, c = jc % 3;
    float acc[NB + 1];
#pragma unroll
    for (int t = 0; t <= NB; ++t) acc[t] = 0.f;
    for (int v = tid; v < V; v += 256) {
        float w = jreg[(size_t)j * V + v];
        int col = v * 3 + c;
#pragma unroll
        for (int k = 0; k < NB; ++k) acc[k] += w * sd[(size_t)k * V3 + col];
        acc[NB] += w * vt[col];
    }
    float* red = reinterpret_cast<float*>(smem);
    int lane = tid & 63, w64 = tid >> 6;
#pragma unroll
    for (int t = 0; t <= NB; ++t) {
        float a = acc[t];
#pragma unroll
        for (int s = 1; s < 64; s <<= 1) a += __shfl_xor(a, s, 64);
        if (lane == 0) red[w64 * 16 + t] = a;
    }
    __syncthreads();
    if (tid <= NB) {
        float s = red[tid] + red[16 + tid] + red[32 + tid] + red[48 + tid];
        if (tid < NB) ws[SJ_OFF + (size_t)tid * 72 + jc] = s;
        else          ws[JT_OFF + jc] = s;
    }
}

// ---------------------------------------------------------------------------
// k_head: scale + J + apf(fragment layout) + FK + an16. One wave per n.
__global__ __launch_bounds__(64) void k_head(const float* __restrict__ pose,
                                             const float* __restrict__ betas,
                                             const float* __restrict__ vt,
                                             const float* __restrict__ sd,
                                             float* __restrict__ ws,
                                             unsigned short* __restrict__ apf,
                                             _Float16* __restrict__ an16) {
    int n = blockIdx.x;
    int tid = threadIdx.x;
    __shared__ float sval[4];
    __shared__ float Jl[NJ * 3];
    __shared__ float G[NJ * 12];
    __shared__ unsigned short pfsh[KP];

    const int idx4[4] = {2802 * 3 + 1, 6262 * 3 + 1, 2237 * 3 + 1, 6728 * 3 + 1};
    if (tid < 4) {
        float a = vt[idx4[tid]];
#pragma unroll
        for (int k = 0; k < NB; ++k)
            a += betas[n * NB + k] * sd[(size_t)k * V3 + idx4[tid]];
        sval[tid] = a;
    }
    __syncthreads();
    float scale = 1.66f / (sval[0] + sval[1] - sval[2] - sval[3]);
    if (tid == 0) ws[SCALE_OFF + n] = scale;

    for (int k = tid; k < KP; k += 64) {
        float v = 0.f;
        if (k < NP) {
            v = pose[(size_t)n * 216 + 9 + k];
            int km = k % 9;
            if (km == 0 || km == 4 || km == 8) v -= 1.f;
        } else if (k < NP + NB) {
            v = scale * betas[n * NB + (k - NP)];
        }
        pfsh[k] = f2bf(v);
    }
    for (int e = tid; e < 72; e += 64) {
        float a = ws[JT_OFF + e];
#pragma unroll
        for (int k = 0; k < NB; ++k)
            a += betas[n * NB + k] * ws[SJ_OFF + (size_t)k * 72 + e];
        Jl[e] = scale * a;
    }
    __syncthreads();
    // apf fragment layout: [(n/16)*7+kk][lane=q*16+(n&15)][8]
    if (tid < 28) {
        int kk = tid >> 2, q = tid & 3;
        s16x8 r;
#pragma unroll
        for (int j = 0; j < 8; ++j) r[j] = (short)pfsh[kk * 32 + q * 8 + j];
        size_t off = ((size_t)(n >> 4) * 7 + kk) * 64 + q * 16 + (n & 15);
        *reinterpret_cast<s16x8*>(&apf[off * 8]) = r;
    }

    const int par[NJ] = {0,0,0,0,1,2,3,4,5,6,7,8,9,9,9,12,13,14,16,17,18,19,20,21};
    if (tid < 12) {
        int r = tid >> 2, c = tid & 3;
        G[tid] = (c < 3) ? pose[(size_t)n * 216 + r * 3 + c] : Jl[r];
    }
    __syncthreads();
    for (int i = 1; i < NJ; ++i) {
        int p = par[i];
        if (tid < 12) {
            int r = tid >> 2, c = tid & 3;
            const float* gp = &G[p * 12 + r * 4];
            float v;
            if (c < 3) {
                const float* Ri = pose + (size_t)n * 216 + i * 9;
                v = gp[0] * Ri[0 * 3 + c] + gp[1] * Ri[1 * 3 + c] + gp[2] * Ri[2 * 3 + c];
            } else {
                float t0 = Jl[i * 3 + 0] - Jl[p * 3 + 0];
                float t1 = Jl[i * 3 + 1] - Jl[p * 3 + 1];
                float t2 = Jl[i * 3 + 2] - Jl[p * 3 + 2];
                v = gp[0] * t0 + gp[1] * t1 + gp[2] * t2 + gp[3];
            }
            G[i * 12 + tid] = v;
        }
        __syncthreads();
    }
    // an16[n][col(16)][k=j(32)]
    for (int e = tid; e < 512; e += 64) {
        int col = e >> 5, j = e & 31;
        float v = 0.f;
        if (col < 12 && j < NJ) {
            int r = col >> 2, c = col & 3;
            if (c < 3) v = G[j * 12 + r * 4 + c];
            else {
                const float* g = &G[j * 12 + r * 4];
                v = g[3] - (g[0] * Jl[j * 3 + 0] + g[1] * Jl[j * 3 + 1] + g[2] * Jl[j * 3 + 2]);
            }
        }
        an16[(size_t)n * 512 + e] = (_Float16)v;
    }
}

// ---------------------------------------------------------------------------
// k_gl: fused pose-GEMM + LBS. R15: stage 2 partitioned by n-slice. Wave w
// handles n in [w*16, w*16+16) -- exactly the sm rows its own stage-1 MFMAs
// produced -- for all 64 block-vertices via 4 register-resident w16 frags.
// Per n: one coalesced 1KB an16 wave-load feeds 4 independent T-MFMAs
// (operand-swapped: lane (m,q) gets T[q][0..3] of vertex g*16+m), apply is
// inline, ds_read_b64 rows are wave-uniform (conflict-free). 2 barriers total.
__global__ __launch_bounds__(256) void k_gl(const unsigned short* __restrict__ apf,
                                            const unsigned short* __restrict__ bp,
                                            const float* __restrict__ vt,
                                            const float* __restrict__ ws,
                                            const _Float16* __restrict__ w16,
                                            const _Float16* __restrict__ an16,
                                            const float* __restrict__ trans,
                                            _Float16* __restrict__ vb) {
    int tid = threadIdx.x;
    int lane = tid & 63, w = tid >> 6;
    int m = lane & 15, q = lane >> 4;
    int cb = blockIdx.x;                 // 0..107  (64-v tile)
    int nb = blockIdx.y;                 // 0..7    (64-n tile)
    int nt = nb * 4 + w;

    // posed verts, packed per-vertex: [n][v(65 pad)][c(4)] fp16 = 33.3 KB.
    // stride per n = 520 B (65*8): 8B-aligned, breaks pow2 banking.
    __shared__ __align__(16) _Float16 sm[64][65][4];
    __shared__ float svt[192];
    __shared__ float ssc[64];
    __shared__ float strans[192];
    if (tid < 192) {
        int col = cb * 192 + tid;
        svt[tid] = (col < V3) ? vt[col] : 0.f;
        strans[tid] = trans[nb * 192 + tid];
    }
    if (tid < 64) ssc[tid] = ws[SCALE_OFF + nb * 64 + tid];

    // ---- stage 1: pose GEMM
    const unsigned short* abase = apf + (size_t)nt * 7 * 512 + lane * 8;
    const unsigned short* bbase = bp + (size_t)cb * 12 * 7 * 512 + lane * 8;

    f32x4 acc[12];
#pragma unroll
    for (int ct = 0; ct < 12; ++ct) acc[ct] = (f32x4){0.f, 0.f, 0.f, 0.f};

#pragma unroll
    for (int kk = 0; kk < 7; ++kk) {
        s16x8 a = *reinterpret_cast<const s16x8*>(abase + kk * 512);
#pragma unroll
        for (int ct = 0; ct < 12; ++ct) {
            s16x8 bfr = *reinterpret_cast<const s16x8*>(bbase + (ct * 7 + kk) * 512);
            acc[ct] = __builtin_amdgcn_mfma_f32_16x16x32_bf16(a, bfr, acc[ct], 0, 0, 0);
        }
    }

    // w16 fragments for all 4 vertex groups (independent of acc; issue early)
    h16x8 wf[4];
#pragma unroll
    for (int g = 0; g < 4; ++g)
        wf[g] = *reinterpret_cast<const h16x8*>(
            &w16[(size_t)(cb * 64 + g * 16 + m) * 32 + q * 8]);

    __syncthreads();          // svt/ssc/strans ready
#pragma unroll
    for (int ct = 0; ct < 12; ++ct) {
        int col_loc = ct * 16 + m;
        int v_loc = col_loc / 3;
        int c = col_loc - 3 * v_loc;
        float vtc = svt[col_loc];
#pragma unroll
        for (int r = 0; r < 4; ++r) {
            int n_loc = w * 16 + q * 4 + r;
            sm[n_loc][v_loc][c] = (_Float16)(acc[ct][r] + ssc[n_loc] * vtc);
        }
    }

    // ---- stage 2: LBS over own n-slice, all 64 vertices
    __syncthreads();                          // sm complete

    const _Float16* anb = an16 + (size_t)(nb * 64 + w * 16) * 512 + m * 32 + q * 8;
    _Float16* vbase = vb + (size_t)(nb * 64 + w * 16) * 3 * VP2 + (size_t)q * VP2
                      + (size_t)cb * 64;
#pragma unroll 2
    for (int i = 0; i < 16; ++i) {
        int nl = w * 16 + i;
        h16x8 bf = *reinterpret_cast<const h16x8*>(anb + (size_t)i * 512);
        f32x4 at[4];
#pragma unroll
        for (int g = 0; g < 4; ++g) {
            f32x4 z = (f32x4){0.f, 0.f, 0.f, 0.f};
            at[g] = __builtin_amdgcn_mfma_f32_16x16x32_f16(bf, wf[g], z, 0, 0, 0);
        }
        if (q < 3) {
            float tr = strans[nl * 3 + q];
#pragma unroll
            for (int g = 0; g < 4; ++g) {
                int vl = g * 16 + m;
                h16x4 p = *reinterpret_cast<const h16x4*>(&sm[nl][vl][0]);
                float r = at[g][0] * (float)p[0] + at[g][1] * (float)p[1]
                        + at[g][2] * (float)p[2] + at[g][3] + tr;
                vbase[(size_t)i * 3 * VP2 + vl] = (_Float16)r;
            }
        }
    }
}

// ---------------------------------------------------------------------------
// k_regm v4: grid (96 nc-tiles x 6 v-splits) = 576 blocks (~9 waves/CU).
// Each wave: 9 K-steps. LDS combine across 4 waves, atomicAdd partials.
__global__ __launch_bounds__(256) void k_regm(const _Float16* __restrict__ rb,
                                              const _Float16* __restrict__ vb,
                                              float* __restrict__ out) {
    int tid = threadIdx.x;
    int lane = tid & 63, w = tid >> 6;
    int m = lane & 15, q = lane >> 4;
    int nct = blockIdx.x;                    // 0..95
    int split = blockIdx.y;                  // 0..5

    const _Float16* brow = vb + (size_t)(nct * 16 + m) * VP2 + q * 8;
    const _Float16* abase = rb + (size_t)m * VP2 + q * 8;
    int vstart = (split * 4 + w) * 288;      // 9 steps of 32 per wave

    f32x4 acc[6];
#pragma unroll
    for (int kt = 0; kt < 6; ++kt) acc[kt] = (f32x4){0.f, 0.f, 0.f, 0.f};

#pragma unroll
    for (int s = 0; s < 9; ++s) {
        int off = vstart + s * 32;
        h16x8 b = *reinterpret_cast<const h16x8*>(brow + off);
#pragma unroll
        for (int kt = 0; kt < 6; ++kt) {
            h16x8 a = *reinterpret_cast<const h16x8*>(abase + (size_t)kt * 16 * VP2 + off);
            acc[kt] = __builtin_amdgcn_mfma_f32_16x16x32_f16(a, b, acc[kt], 0, 0, 0);
        }
    }
    __shared__ float sm[4][6][256];          // 24 KB
#pragma unroll
    for (int kt = 0; kt < 6; ++kt)
#pragma unroll
        for (int r = 0; r < 4; ++r)
            sm[w][kt][(q * 4 + r) * 16 + m] = acc[kt][r];
    __syncthreads();
    for (int e = tid; e < 6 * 256; e += 256) {
        int kt = e >> 8, i = e & 255;
        float s = sm[0][kt][i] + sm[1][kt][i] + sm[2][kt][i] + sm[3][kt][i];
        int k = kt * 16 + (i >> 4);
        int nc = nct * 16 + (i & 15);
        if (k < NK) {
            int n = nc / 3, c = nc - n * 3;
            atomicAdd(&out[(size_t)n * (NK * 3) + k * 3 + c], s);
        }
    }
}

// ---------------------------------------------------------------------------
extern "C" void kernel_launch(void* const* d_in, const int* in_sizes, int n_in,
                              void* d_out, int out_size, void* d_ws, size_t ws_size,
                              hipStream_t stream) {
    const float* pose  = (const float*)d_in[0];
    const float* betas = (const float*)d_in[1];
    const float* trans = (const float*)d_in[2];
    const float* vt    = (const float*)d_in[3];
    const float* sd    = (const float*)d_in[4];
    const float* jreg  = (const float*)d_in[5];
    const float* pdirs = (const float*)d_in[6];
    const float* lbsw  = (const float*)d_in[7];
    const float* b25   = (const float*)d_in[8];
    const float* face  = (const float*)d_in[9];
    float* ws  = (float*)d_ws;
    float* out = (float*)d_out;
    unsigned short* bf  = (unsigned short*)(ws + BF_OFF);
    unsigned short* apf = bf + APF_U;
    unsigned short* bp  = bf + BP_U;
    _Float16* rb  = (_Float16*)(bf + RB_U);
    _Float16* vb  = (_Float16*)(bf + VB_U);
    _Float16* w16 = (_Float16*)(ws + WT_OFF);
    _Float16* an16 = (_Float16*)(ws + AN_OFF);

    hipMemsetAsync(d_out, 0, (size_t)out_size * sizeof(float), stream);

    k_static<<<NB_STATIC, 256, 0, stream>>>(pdirs, sd, jreg, vt, lbsw, b25, face,
                                            bp, rb, w16, ws);
    k_head  <<<N, 64, 0, stream>>>(pose, betas, vt, sd, ws, apf, an16);
    k_gl    <<<dim3(108, 8), 256, 0, stream>>>(apf, bp, vt, ws, w16, an16, trans, vb);
    k_regm  <<<dim3(96, 6), 256, 0, stream>>>(rb, vb, out);
}

// Round 3
// 169.670 us; speedup vs baseline: 1.3387x; 1.1861x over previous
//
#include <hip/hip_runtime.h>

// SMPL body model forward.
// R16: k_gl block-geometry split. R13/R14/R15 (55-84us) showed stage-2
// restructures don't move the needle: with 864 blocks (3.4/CU) the whole
// grid is co-resident and duration == single-block critical path at ~1.4
// waves/SIMD (occ 17.6%) -- pure unhidden latency. Fix: n-tile 64->32,
// grid (108,16)=1728 blocks, sm halves to 16.6KB -> ~6.75 blocks/CU =
// 27 waves/CU (2x). Per-block work halves (stage1: 2 n-grp x 2 col-half
// per wave; stage2: 8 n-rows/wave); totals unchanged. acc 12->6 frees VGPRs.

constexpr int N   = 512;
constexpr int V   = 6890;
constexpr int V3  = V * 3;        // 20670
constexpr int NJ  = 24;
constexpr int NB  = 10;
constexpr int NP  = 207;
constexpr int NK  = 95;
constexpr int KP  = 224;          // padded K for pose GEMM
constexpr int VP2 = 6912;         // V padded (108*64)

// workspace layout (float offsets)
constexpr size_t SCALE_OFF = (size_t)N * V3;                  // N
constexpr size_t SJ_OFF    = SCALE_OFF + N;                   // NB*72
constexpr size_t JT_OFF    = SJ_OFF + (size_t)NB * 72;        // 72
constexpr size_t J_OFF     = JT_OFF + 72;
constexpr size_t A_OFF     = J_OFF + (size_t)N * 72;
constexpr size_t BF_OFF    = A_OFF + (size_t)N * 288;         // bf16/fp16 region
// region (ushort offsets)
constexpr size_t APF_U     = 0;                               // apf_sw [N/16][7][64][8] bf16
constexpr int    BP_COLS   = 20736;                           // 108*192 col pad
constexpr size_t BP_U      = (size_t)N * KP;                  // bp_sw [1296][7][64][8] bf16
constexpr size_t RB_U      = BP_U + (size_t)BP_COLS * KP;     // reg fp16 [96][VP2]
constexpr size_t VB_U      = RB_U + (size_t)96 * VP2;         // verts fp16 [N][3][VP2]
constexpr size_t BF_END_U  = VB_U + (size_t)N * 3 * VP2;
constexpr size_t WT_OFF    = BF_OFF + (BF_END_U + 1) / 2;     // w16 fp16 [VP2][32]
constexpr size_t AN_OFF    = WT_OFF + (size_t)VP2 * 32 / 2;   // an16 fp16 [N][16][32]

// k_static section block counts
constexpr int NB_REGBF = (96 * VP2) / 256;   // 2592
constexpr int NB_BT    = BP_COLS / 64;       // 324
constexpr int NB_WT    = VP2 / 256;          // 27
constexpr int NB_PRE   = 72;
constexpr int NB_STATIC = NB_REGBF + NB_BT + NB_WT + NB_PRE;

typedef short s16x8 __attribute__((ext_vector_type(8)));
typedef _Float16 h16x8 __attribute__((ext_vector_type(8)));
typedef _Float16 h16x4 __attribute__((ext_vector_type(4)));
typedef float f32x4 __attribute__((ext_vector_type(4)));

__device__ inline unsigned short f2bf(float f) {
    unsigned u = __float_as_uint(f);
    u += 0x7fffu + ((u >> 16) & 1u);   // round-to-nearest-even
    return (unsigned short)(u >> 16);
}

// ---------------------------------------------------------------------------
// k_static: sectioned batch-independent prep (regbf | bt | wt | pre).
__global__ __launch_bounds__(256) void k_static(const float* __restrict__ pdirs,
                                                const float* __restrict__ sd,
                                                const float* __restrict__ jreg,
                                                const float* __restrict__ vt,
                                                const float* __restrict__ lbsw,
                                                const float* __restrict__ b25,
                                                const float* __restrict__ face,
                                                unsigned short* __restrict__ bp,
                                                _Float16* __restrict__ rb,
                                                _Float16* __restrict__ w16,
                                                float* __restrict__ ws) {
    __shared__ unsigned short smem[KP * 64];     // 28 KB, reused per section
    int b = blockIdx.x;
    int tid = threadIdx.x;

    if (b < NB_REGBF) {
        int t = b * 256 + tid;
        int k = t / VP2, v = t - k * VP2;
        float val = 0.f;
        if (v < V && k < NK)
            val = (k < 25) ? b25[(size_t)k * V + v] : face[(size_t)(k - 25) * V + v];
        rb[t] = (_Float16)val;
        return;
    }
    b -= NB_REGBF;
    if (b < NB_BT) {
        // stage [k][cl] then emit FRAGMENT layout bp[(ctg*7+kk)*64+lane][8]
        int c0 = b * 64;
#pragma unroll 4
        for (int i = 0; i < 56; ++i) {
            int e = tid + 256 * i;
            int k = e >> 6, cl = e & 63;
            int col = c0 + cl;
            float v = 0.f;
            if (col < V3) {
                if (k < NP) v = pdirs[(size_t)k * V3 + col];
                else if (k < NP + NB) v = sd[(size_t)(k - NP) * V3 + col];
            }
            smem[k * 64 + cl] = f2bf(v);
        }
        __syncthreads();
        for (int i = 0; i < 7; ++i) {
            int u = tid + 256 * i;                // 0..1791
            int ct_loc = u / 448;
            int rem = u - ct_loc * 448;
            int kk = rem >> 6, lane = rem & 63;
            int m = lane & 15, q = lane >> 4;
            s16x8 r;
#pragma unroll
            for (int j = 0; j < 8; ++j)
                r[j] = (short)smem[(kk * 32 + q * 8 + j) * 64 + ct_loc * 16 + m];
            size_t ctg = (size_t)(c0 >> 4) + ct_loc;
            *reinterpret_cast<s16x8*>(&bp[((ctg * 7 + kk) * 64 + lane) * 8]) = r;
        }
        return;
    }
    b -= NB_BT;
    if (b < NB_WT) {
        // w16[v][k=j] fp16, A-operand layout for the T-MFMA
        float* t = reinterpret_cast<float*>(smem);
        int v0 = b * 256;
        for (int e = tid; e < 256 * 24; e += 256) {
            int g = v0 * 24 + e;
            float val = (g < V * NJ) ? lbsw[g] : 0.f;
            int vv = e / 24, j = e - vv * 24;
            t[vv * 25 + j] = val;
        }
        __syncthreads();
        _Float16* dst = w16 + (size_t)(v0 + tid) * 32;
#pragma unroll
        for (int j = 0; j < 32; ++j)
            dst[j] = (j < NJ) ? (_Float16)t[tid * 25 + j] : (_Float16)0.f;
        return;
    }
    b -= NB_WT;
    // pre: SJ / Jt, block per jc, shuffle reduce
    int jc = b;
    int j = jc / 3, c = jc % 3;
    float acc[NB + 1];
#pragma unroll
    for (int t = 0; t <= NB; ++t) acc[t] = 0.f;
    for (int v = tid; v < V; v += 256) {
        float w = jreg[(size_t)j * V + v];
        int col = v * 3 + c;
#pragma unroll
        for (int k = 0; k < NB; ++k) acc[k] += w * sd[(size_t)k * V3 + col];
        acc[NB] += w * vt[col];
    }
    float* red = reinterpret_cast<float*>(smem);
    int lane = tid & 63, w64 = tid >> 6;
#pragma unroll
    for (int t = 0; t <= NB; ++t) {
        float a = acc[t];
#pragma unroll
        for (int s = 1; s < 64; s <<= 1) a += __shfl_xor(a, s, 64);
        if (lane == 0) red[w64 * 16 + t] = a;
    }
    __syncthreads();
    if (tid <= NB) {
        float s = red[tid] + red[16 + tid] + red[32 + tid] + red[48 + tid];
        if (tid < NB) ws[SJ_OFF + (size_t)tid * 72 + jc] = s;
        else          ws[JT_OFF + jc] = s;
    }
}

// ---------------------------------------------------------------------------
// k_head: scale + J + apf(fragment layout) + FK + an16. One wave per n.
__global__ __launch_bounds__(64) void k_head(const float* __restrict__ pose,
                                             const float* __restrict__ betas,
                                             const float* __restrict__ vt,
                                             const float* __restrict__ sd,
                                             float* __restrict__ ws,
                                             unsigned short* __restrict__ apf,
                                             _Float16* __restrict__ an16) {
    int n = blockIdx.x;
    int tid = threadIdx.x;
    __shared__ float sval[4];
    __shared__ float Jl[NJ * 3];
    __shared__ float G[NJ * 12];
    __shared__ unsigned short pfsh[KP];

    const int idx4[4] = {2802 * 3 + 1, 6262 * 3 + 1, 2237 * 3 + 1, 6728 * 3 + 1};
    if (tid < 4) {
        float a = vt[idx4[tid]];
#pragma unroll
        for (int k = 0; k < NB; ++k)
            a += betas[n * NB + k] * sd[(size_t)k * V3 + idx4[tid]];
        sval[tid] = a;
    }
    __syncthreads();
    float scale = 1.66f / (sval[0] + sval[1] - sval[2] - sval[3]);
    if (tid == 0) ws[SCALE_OFF + n] = scale;

    for (int k = tid; k < KP; k += 64) {
        float v = 0.f;
        if (k < NP) {
            v = pose[(size_t)n * 216 + 9 + k];
            int km = k % 9;
            if (km == 0 || km == 4 || km == 8) v -= 1.f;
        } else if (k < NP + NB) {
            v = scale * betas[n * NB + (k - NP)];
        }
        pfsh[k] = f2bf(v);
    }
    for (int e = tid; e < 72; e += 64) {
        float a = ws[JT_OFF + e];
#pragma unroll
        for (int k = 0; k < NB; ++k)
            a += betas[n * NB + k] * ws[SJ_OFF + (size_t)k * 72 + e];
        Jl[e] = scale * a;
    }
    __syncthreads();
    // apf fragment layout: [(n/16)*7+kk][lane=q*16+(n&15)][8]
    if (tid < 28) {
        int kk = tid >> 2, q = tid & 3;
        s16x8 r;
#pragma unroll
        for (int j = 0; j < 8; ++j) r[j] = (short)pfsh[kk * 32 + q * 8 + j];
        size_t off = ((size_t)(n >> 4) * 7 + kk) * 64 + q * 16 + (n & 15);
        *reinterpret_cast<s16x8*>(&apf[off * 8]) = r;
    }

    const int par[NJ] = {0,0,0,0,1,2,3,4,5,6,7,8,9,9,9,12,13,14,16,17,18,19,20,21};
    if (tid < 12) {
        int r = tid >> 2, c = tid & 3;
        G[tid] = (c < 3) ? pose[(size_t)n * 216 + r * 3 + c] : Jl[r];
    }
    __syncthreads();
    for (int i = 1; i < NJ; ++i) {
        int p = par[i];
        if (tid < 12) {
            int r = tid >> 2, c = tid & 3;
            const float* gp = &G[p * 12 + r * 4];
            float v;
            if (c < 3) {
                const float* Ri = pose + (size_t)n * 216 + i * 9;
                v = gp[0] * Ri[0 * 3 + c] + gp[1] * Ri[1 * 3 + c] + gp[2] * Ri[2 * 3 + c];
            } else {
                float t0 = Jl[i * 3 + 0] - Jl[p * 3 + 0];
                float t1 = Jl[i * 3 + 1] - Jl[p * 3 + 1];
                float t2 = Jl[i * 3 + 2] - Jl[p * 3 + 2];
                v = gp[0] * t0 + gp[1] * t1 + gp[2] * t2 + gp[3];
            }
            G[i * 12 + tid] = v;
        }
        __syncthreads();
    }
    // an16[n][col(16)][k=j(32)]
    for (int e = tid; e < 512; e += 64) {
        int col = e >> 5, j = e & 31;
        float v = 0.f;
        if (col < 12 && j < NJ) {
            int r = col >> 2, c = col & 3;
            if (c < 3) v = G[j * 12 + r * 4 + c];
            else {
                const float* g = &G[j * 12 + r * 4];
                v = g[3] - (g[0] * Jl[j * 3 + 0] + g[1] * Jl[j * 3 + 1] + g[2] * Jl[j * 3 + 2]);
            }
        }
        an16[(size_t)n * 512 + e] = (_Float16)v;
    }
}

// ---------------------------------------------------------------------------
// k_gl: fused pose-GEMM + LBS, 32-n tiles. Wave w: wg=w&1 picks the 16-n
// group, wc=w>>1 picks the 96-col half (6 ct x 7 kk = 42 MFMAs). Stage 2:
// wave w owns 8 n-rows x 64 verts via 4 register w16 frags (operand-swapped
// T-MFMA: lane (m,q) gets T[q][0..3] of vertex g*16+m). 2 barriers total.
__global__ __launch_bounds__(256) void k_gl(const unsigned short* __restrict__ apf,
                                            const unsigned short* __restrict__ bp,
                                            const float* __restrict__ vt,
                                            const float* __restrict__ ws,
                                            const _Float16* __restrict__ w16,
                                            const _Float16* __restrict__ an16,
                                            const float* __restrict__ trans,
                                            _Float16* __restrict__ vb) {
    int tid = threadIdx.x;
    int lane = tid & 63, w = tid >> 6;
    int m = lane & 15, q = lane >> 4;
    int cb = blockIdx.x;                 // 0..107  (64-v tile)
    int nb = blockIdx.y;                 // 0..15   (32-n tile)
    int wg = w & 1;                      // n 16-group within tile
    int wc = w >> 1;                     // col 96-half

    // posed verts [n(32)][v(65 pad)][c(4)] fp16 = 16.6 KB; row stride 520 B.
    __shared__ __align__(16) _Float16 sm[32][65][4];
    __shared__ float svt[192];
    __shared__ float ssc[32];
    __shared__ float strans[96];
    if (tid < 192) {
        int col = cb * 192 + tid;
        svt[tid] = (col < V3) ? vt[col] : 0.f;
    }
    if (tid < 96) strans[tid] = trans[nb * 96 + tid];
    if (tid < 32) ssc[tid] = ws[SCALE_OFF + nb * 32 + tid];

    // ---- stage 1: pose GEMM (16 n x 96 cols per wave)
    const unsigned short* abase = apf + ((size_t)(nb * 2 + wg) * 7) * 512 + lane * 8;
    const unsigned short* bbase = bp + ((size_t)cb * 12 + wc * 6) * 7 * 512 + lane * 8;

    f32x4 acc[6];
#pragma unroll
    for (int ct = 0; ct < 6; ++ct) acc[ct] = (f32x4){0.f, 0.f, 0.f, 0.f};

#pragma unroll
    for (int kk = 0; kk < 7; ++kk) {
        s16x8 a = *reinterpret_cast<const s16x8*>(abase + kk * 512);
#pragma unroll
        for (int ct = 0; ct < 6; ++ct) {
            s16x8 bfr = *reinterpret_cast<const s16x8*>(bbase + (ct * 7 + kk) * 512);
            acc[ct] = __builtin_amdgcn_mfma_f32_16x16x32_bf16(a, bfr, acc[ct], 0, 0, 0);
        }
    }

    // w16 fragments for all 4 vertex groups (independent of acc; issue early)
    h16x8 wf[4];
#pragma unroll
    for (int g = 0; g < 4; ++g)
        wf[g] = *reinterpret_cast<const h16x8*>(
            &w16[(size_t)(cb * 64 + g * 16 + m) * 32 + q * 8]);

    __syncthreads();          // svt/ssc/strans ready
#pragma unroll
    for (int ct = 0; ct < 6; ++ct) {
        int col_loc = (wc * 6 + ct) * 16 + m;
        int v_loc = col_loc / 3;
        int c = col_loc - 3 * v_loc;
        float vtc = svt[col_loc];
#pragma unroll
        for (int r = 0; r < 4; ++r) {
            int n_loc = wg * 16 + q * 4 + r;
            sm[n_loc][v_loc][c] = (_Float16)(acc[ct][r] + ssc[n_loc] * vtc);
        }
    }

    // ---- stage 2: LBS, wave w owns n-rows [w*8, w*8+8) x all 64 verts
    __syncthreads();                          // sm complete

    const _Float16* anb = an16 + (size_t)(nb * 32 + w * 8) * 512 + m * 32 + q * 8;
    _Float16* vbase = vb + (size_t)(nb * 32 + w * 8) * 3 * VP2 + (size_t)q * VP2
                      + (size_t)cb * 64;
#pragma unroll
    for (int half = 0; half < 2; ++half) {
        h16x8 bf8[4];
#pragma unroll
        for (int i = 0; i < 4; ++i)
            bf8[i] = *reinterpret_cast<const h16x8*>(anb + (size_t)(half * 4 + i) * 512);
#pragma unroll
        for (int i = 0; i < 4; ++i) {
            int nl = w * 8 + half * 4 + i;
            f32x4 at[4];
#pragma unroll
            for (int g = 0; g < 4; ++g) {
                f32x4 z = (f32x4){0.f, 0.f, 0.f, 0.f};
                at[g] = __builtin_amdgcn_mfma_f32_16x16x32_f16(bf8[i], wf[g], z, 0, 0, 0);
            }
            if (q < 3) {
                float tr = strans[nl * 3 + q];
#pragma unroll
                for (int g = 0; g < 4; ++g) {
                    int vl = g * 16 + m;
                    h16x4 p = *reinterpret_cast<const h16x4*>(&sm[nl][vl][0]);
                    float r = at[g][0] * (float)p[0] + at[g][1] * (float)p[1]
                            + at[g][2] * (float)p[2] + at[g][3] + tr;
                    vbase[(size_t)(half * 4 + i) * 3 * VP2 + vl] = (_Float16)r;
                }
            }
        }
    }
}

// ---------------------------------------------------------------------------
// k_regm v4: grid (96 nc-tiles x 6 v-splits) = 576 blocks (~9 waves/CU).
// Each wave: 9 K-steps. LDS combine across 4 waves, atomicAdd partials.
__global__ __launch_bounds__(256) void k_regm(const _Float16* __restrict__ rb,
                                              const _Float16* __restrict__ vb,
                                              float* __restrict__ out) {
    int tid = threadIdx.x;
    int lane = tid & 63, w = tid >> 6;
    int m = lane & 15, q = lane >> 4;
    int nct = blockIdx.x;                    // 0..95
    int split = blockIdx.y;                  // 0..5

    const _Float16* brow = vb + (size_t)(nct * 16 + m) * VP2 + q * 8;
    const _Float16* abase = rb + (size_t)m * VP2 + q * 8;
    int vstart = (split * 4 + w) * 288;      // 9 steps of 32 per wave

    f32x4 acc[6];
#pragma unroll
    for (int kt = 0; kt < 6; ++kt) acc[kt] = (f32x4){0.f, 0.f, 0.f, 0.f};

#pragma unroll
    for (int s = 0; s < 9; ++s) {
        int off = vstart + s * 32;
        h16x8 b = *reinterpret_cast<const h16x8*>(brow + off);
#pragma unroll
        for (int kt = 0; kt < 6; ++kt) {
            h16x8 a = *reinterpret_cast<const h16x8*>(abase + (size_t)kt * 16 * VP2 + off);
            acc[kt] = __builtin_amdgcn_mfma_f32_16x16x32_f16(a, b, acc[kt], 0, 0, 0);
        }
    }
    __shared__ float sm[4][6][256];          // 24 KB
#pragma unroll
    for (int kt = 0; kt < 6; ++kt)
#pragma unroll
        for (int r = 0; r < 4; ++r)
            sm[w][kt][(q * 4 + r) * 16 + m] = acc[kt][r];
    __syncthreads();
    for (int e = tid; e < 6 * 256; e += 256) {
        int kt = e >> 8, i = e & 255;
        float s = sm[0][kt][i] + sm[1][kt][i] + sm[2][kt][i] + sm[3][kt][i];
        int k = kt * 16 + (i >> 4);
        int nc = nct * 16 + (i & 15);
        if (k < NK) {
            int n = nc / 3, c = nc - n * 3;
            atomicAdd(&out[(size_t)n * (NK * 3) + k * 3 + c], s);
        }
    }
}

// ---------------------------------------------------------------------------
extern "C" void kernel_launch(void* const* d_in, const int* in_sizes, int n_in,
                              void* d_out, int out_size, void* d_ws, size_t ws_size,
                              hipStream_t stream) {
    const float* pose  = (const float*)d_in[0];
    const float* betas = (const float*)d_in[1];
    const float* trans = (const float*)d_in[2];
    const float* vt    = (const float*)d_in[3];
    const float* sd    = (const float*)d_in[4];
    const float* jreg  = (const float*)d_in[5];
    const float* pdirs = (const float*)d_in[6];
    const float* lbsw  = (const float*)d_in[7];
    const float* b25   = (const float*)d_in[8];
    const float* face  = (const float*)d_in[9];
    float* ws  = (float*)d_ws;
    float* out = (float*)d_out;
    unsigned short* bf  = (unsigned short*)(ws + BF_OFF);
    unsigned short* apf = bf + APF_U;
    unsigned short* bp  = bf + BP_U;
    _Float16* rb  = (_Float16*)(bf + RB_U);
    _Float16* vb  = (_Float16*)(bf + VB_U);
    _Float16* w16 = (_Float16*)(ws + WT_OFF);
    _Float16* an16 = (_Float16*)(ws + AN_OFF);

    hipMemsetAsync(d_out, 0, (size_t)out_size * sizeof(float), stream);

    k_static<<<NB_STATIC, 256, 0, stream>>>(pdirs, sd, jreg, vt, lbsw, b25, face,
                                            bp, rb, w16, ws);
    k_head  <<<N, 64, 0, stream>>>(pose, betas, vt, sd, ws, apf, an16);
    k_gl    <<<dim3(108, 16), 256, 0, stream>>>(apf, bp, vt, ws, w16, an16, trans, vb);
    k_regm  <<<dim3(96, 6), 256, 0, stream>>>(rb, vb, out);
}

// Round 4
// 163.926 us; speedup vs baseline: 1.3856x; 1.0350x over previous
//
#include <hip/hip_runtime.h>

// SMPL body model forward.
// R17: three independent edits.
//  (1) k_gl tile (64v x 32n) -> (32v x 32n), grid (216,16)=3456 blocks,
//      LDS ~9.4 KB -> ~32 waves/CU resident (was 27). bp L2 traffic
//      unchanged (blocks read only their half-slice).
//  (2) rb stored in MFMA A-fragment layout (written by k_static.regbf):
//      k_regm's 54 A-loads/wave become contiguous 1KB wave-loads (4 cache
//      lines) instead of 16-row scatters at 13.8KB stride.
//  (3) k_static.bt LDS pad 64->66 ushorts: gather reads now stride 33
//      dwords (+1 bank per j) -- kills the 8-way conflict.
// e2e fit so far: e2e = C + k_gl, C~141.5 (incl ~86us harness ws-poison
// fills), k_gl~28. Targets: k_gl ~18, k_regm -4..8, k_static -1..2.

constexpr int N   = 512;
constexpr int V   = 6890;
constexpr int V3  = V * 3;        // 20670
constexpr int NJ  = 24;
constexpr int NB  = 10;
constexpr int NP  = 207;
constexpr int NK  = 95;
constexpr int KP  = 224;          // padded K for pose GEMM
constexpr int VP2 = 6912;         // V padded (108*64)

// workspace layout (float offsets)
constexpr size_t SCALE_OFF = (size_t)N * V3;                  // N
constexpr size_t SJ_OFF    = SCALE_OFF + N;                   // NB*72
constexpr size_t JT_OFF    = SJ_OFF + (size_t)NB * 72;        // 72
constexpr size_t J_OFF     = JT_OFF + 72;
constexpr size_t A_OFF     = J_OFF + (size_t)N * 72;
constexpr size_t BF_OFF    = A_OFF + (size_t)N * 288;         // bf16/fp16 region
// region (ushort offsets)
constexpr size_t APF_U     = 0;                               // apf_sw [N/16][7][64][8] bf16
constexpr int    BP_COLS   = 20736;                           // 108*192 col pad
constexpr size_t BP_U      = (size_t)N * KP;                  // bp_sw [1296][7][64][8] bf16
constexpr size_t RB_U      = BP_U + (size_t)BP_COLS * KP;     // reg fp16 frag [6][216][64][8]
constexpr size_t VB_U      = RB_U + (size_t)96 * VP2;         // verts fp16 [N][3][VP2]
constexpr size_t BF_END_U  = VB_U + (size_t)N * 3 * VP2;
constexpr size_t WT_OFF    = BF_OFF + (BF_END_U + 1) / 2;     // w16 fp16 [VP2][32]
constexpr size_t AN_OFF    = WT_OFF + (size_t)VP2 * 32 / 2;   // an16 fp16 [N][16][32]

// k_static section block counts
constexpr int NB_REGBF = (96 * VP2) / 256;   // 2592
constexpr int NB_BT    = BP_COLS / 64;       // 324
constexpr int NB_WT    = VP2 / 256;          // 27
constexpr int NB_PRE   = 72;
constexpr int NB_STATIC = NB_REGBF + NB_BT + NB_WT + NB_PRE;

typedef short s16x8 __attribute__((ext_vector_type(8)));
typedef _Float16 h16x8 __attribute__((ext_vector_type(8)));
typedef _Float16 h16x4 __attribute__((ext_vector_type(4)));
typedef float f32x4 __attribute__((ext_vector_type(4)));

__device__ inline unsigned short f2bf(float f) {
    unsigned u = __float_as_uint(f);
    u += 0x7fffu + ((u >> 16) & 1u);   // round-to-nearest-even
    return (unsigned short)(u >> 16);
}

// ---------------------------------------------------------------------------
// k_static: sectioned batch-independent prep (regbf | bt | wt | pre).
__global__ __launch_bounds__(256) void k_static(const float* __restrict__ pdirs,
                                                const float* __restrict__ sd,
                                                const float* __restrict__ jreg,
                                                const float* __restrict__ vt,
                                                const float* __restrict__ lbsw,
                                                const float* __restrict__ b25,
                                                const float* __restrict__ face,
                                                unsigned short* __restrict__ bp,
                                                _Float16* __restrict__ rb,
                                                _Float16* __restrict__ w16,
                                                float* __restrict__ ws) {
    __shared__ unsigned short smem[KP * 66];     // 29.6 KB, reused per section
    int b = blockIdx.x;
    int tid = threadIdx.x;

    if (b < NB_REGBF) {
        // rb in MFMA A-fragment layout for k_regm:
        // afr[((kt*216+step)*64 + q8*16 + m16)*8 + j] = reg[k=kt*16+m16][v],
        // step=v/32, q8=(v%32)/8, j=v%8.
        int t = b * 256 + tid;
        int k = t / VP2, v = t - k * VP2;
        float val = 0.f;
        if (v < V && k < NK)
            val = (k < 25) ? b25[(size_t)k * V + v] : face[(size_t)(k - 25) * V + v];
        int kt = k >> 4, m16 = k & 15;
        int step = v >> 5, q8 = (v >> 3) & 3, j = v & 7;
        rb[((size_t)(kt * 216 + step) * 64 + q8 * 16 + m16) * 8 + j] = (_Float16)val;
        return;
    }
    b -= NB_REGBF;
    if (b < NB_BT) {
        // stage [k][cl] (stride 66: conflict-free gather) then emit FRAGMENT
        // layout bp[(ctg*7+kk)*64+lane][8]
        int c0 = b * 64;
#pragma unroll 4
        for (int i = 0; i < 56; ++i) {
            int e = tid + 256 * i;
            int k = e >> 6, cl = e & 63;
            int col = c0 + cl;
            float v = 0.f;
            if (col < V3) {
                if (k < NP) v = pdirs[(size_t)k * V3 + col];
                else if (k < NP + NB) v = sd[(size_t)(k - NP) * V3 + col];
            }
            smem[k * 66 + cl] = f2bf(v);
        }
        __syncthreads();
        for (int i = 0; i < 7; ++i) {
            int u = tid + 256 * i;                // 0..1791
            int ct_loc = u / 448;
            int rem = u - ct_loc * 448;
            int kk = rem >> 6, lane = rem & 63;
            int m = lane & 15, q = lane >> 4;
            s16x8 r;
#pragma unroll
            for (int j = 0; j < 8; ++j)
                r[j] = (short)smem[(kk * 32 + q * 8 + j) * 66 + ct_loc * 16 + m];
            size_t ctg = (size_t)(c0 >> 4) + ct_loc;
            *reinterpret_cast<s16x8*>(&bp[((ctg * 7 + kk) * 64 + lane) * 8]) = r;
        }
        return;
    }
    b -= NB_BT;
    if (b < NB_WT) {
        // w16[v][k=j] fp16, A-operand layout for the T-MFMA
        float* t = reinterpret_cast<float*>(smem);
        int v0 = b * 256;
        for (int e = tid; e < 256 * 24; e += 256) {
            int g = v0 * 24 + e;
            float val = (g < V * NJ) ? lbsw[g] : 0.f;
            int vv = e / 24, j = e - vv * 24;
            t[vv * 25 + j] = val;
        }
        __syncthreads();
        _Float16* dst = w16 + (size_t)(v0 + tid) * 32;
#pragma unroll
        for (int j = 0; j < 32; ++j)
            dst[j] = (j < NJ) ? (_Float16)t[tid * 25 + j] : (_Float16)0.f;
        return;
    }
    b -= NB_WT;
    // pre: SJ / Jt, block per jc, shuffle reduce
    int jc = b;
    int j = jc / 3, c = jc % 3;
    float acc[NB + 1];
#pragma unroll
    for (int t = 0; t <= NB; ++t) acc[t] = 0.f;
    for (int v = tid; v < V; v += 256) {
        float w = jreg[(size_t)j * V + v];
        int col = v * 3 + c;
#pragma unroll
        for (int k = 0; k < NB; ++k) acc[k] += w * sd[(size_t)k * V3 + col];
        acc[NB] += w * vt[col];
    }
    float* red = reinterpret_cast<float*>(smem);
    int lane = tid & 63, w64 = tid >> 6;
#pragma unroll
    for (int t = 0; t <= NB; ++t) {
        float a = acc[t];
#pragma unroll
        for (int s = 1; s < 64; s <<= 1) a += __shfl_xor(a, s, 64);
        if (lane == 0) red[w64 * 16 + t] = a;
    }
    __syncthreads();
    if (tid <= NB) {
        float s = red[tid] + red[16 + tid] + red[32 + tid] + red[48 + tid];
        if (tid < NB) ws[SJ_OFF + (size_t)tid * 72 + jc] = s;
        else          ws[JT_OFF + jc] = s;
    }
}

// ---------------------------------------------------------------------------
// k_head: scale + J + apf(fragment layout) + FK + an16. One wave per n.
__global__ __launch_bounds__(64) void k_head(const float* __restrict__ pose,
                                             const float* __restrict__ betas,
                                             const float* __restrict__ vt,
                                             const float* __restrict__ sd,
                                             float* __restrict__ ws,
                                             unsigned short* __restrict__ apf,
                                             _Float16* __restrict__ an16) {
    int n = blockIdx.x;
    int tid = threadIdx.x;
    __shared__ float sval[4];
    __shared__ float Jl[NJ * 3];
    __shared__ float G[NJ * 12];
    __shared__ unsigned short pfsh[KP];

    const int idx4[4] = {2802 * 3 + 1, 6262 * 3 + 1, 2237 * 3 + 1, 6728 * 3 + 1};
    if (tid < 4) {
        float a = vt[idx4[tid]];
#pragma unroll
        for (int k = 0; k < NB; ++k)
            a += betas[n * NB + k] * sd[(size_t)k * V3 + idx4[tid]];
        sval[tid] = a;
    }
    __syncthreads();
    float scale = 1.66f / (sval[0] + sval[1] - sval[2] - sval[3]);
    if (tid == 0) ws[SCALE_OFF + n] = scale;

    for (int k = tid; k < KP; k += 64) {
        float v = 0.f;
        if (k < NP) {
            v = pose[(size_t)n * 216 + 9 + k];
            int km = k % 9;
            if (km == 0 || km == 4 || km == 8) v -= 1.f;
        } else if (k < NP + NB) {
            v = scale * betas[n * NB + (k - NP)];
        }
        pfsh[k] = f2bf(v);
    }
    for (int e = tid; e < 72; e += 64) {
        float a = ws[JT_OFF + e];
#pragma unroll
        for (int k = 0; k < NB; ++k)
            a += betas[n * NB + k] * ws[SJ_OFF + (size_t)k * 72 + e];
        Jl[e] = scale * a;
    }
    __syncthreads();
    // apf fragment layout: [(n/16)*7+kk][lane=q*16+(n&15)][8]
    if (tid < 28) {
        int kk = tid >> 2, q = tid & 3;
        s16x8 r;
#pragma unroll
        for (int j = 0; j < 8; ++j) r[j] = (short)pfsh[kk * 32 + q * 8 + j];
        size_t off = ((size_t)(n >> 4) * 7 + kk) * 64 + q * 16 + (n & 15);
        *reinterpret_cast<s16x8*>(&apf[off * 8]) = r;
    }

    const int par[NJ] = {0,0,0,0,1,2,3,4,5,6,7,8,9,9,9,12,13,14,16,17,18,19,20,21};
    if (tid < 12) {
        int r = tid >> 2, c = tid & 3;
        G[tid] = (c < 3) ? pose[(size_t)n * 216 + r * 3 + c] : Jl[r];
    }
    __syncthreads();
    for (int i = 1; i < NJ; ++i) {
        int p = par[i];
        if (tid < 12) {
            int r = tid >> 2, c = tid & 3;
            const float* gp = &G[p * 12 + r * 4];
            float v;
            if (c < 3) {
                const float* Ri = pose + (size_t)n * 216 + i * 9;
                v = gp[0] * Ri[0 * 3 + c] + gp[1] * Ri[1 * 3 + c] + gp[2] * Ri[2 * 3 + c];
            } else {
                float t0 = Jl[i * 3 + 0] - Jl[p * 3 + 0];
                float t1 = Jl[i * 3 + 1] - Jl[p * 3 + 1];
                float t2 = Jl[i * 3 + 2] - Jl[p * 3 + 2];
                v = gp[0] * t0 + gp[1] * t1 + gp[2] * t2 + gp[3];
            }
            G[i * 12 + tid] = v;
        }
        __syncthreads();
    }
    // an16[n][col(16)][k=j(32)]
    for (int e = tid; e < 512; e += 64) {
        int col = e >> 5, j = e & 31;
        float v = 0.f;
        if (col < 12 && j < NJ) {
            int r = col >> 2, c = col & 3;
            if (c < 3) v = G[j * 12 + r * 4 + c];
            else {
                const float* g = &G[j * 12 + r * 4];
                v = g[3] - (g[0] * Jl[j * 3 + 0] + g[1] * Jl[j * 3 + 1] + g[2] * Jl[j * 3 + 2]);
            }
        }
        an16[(size_t)n * 512 + e] = (_Float16)v;
    }
}

// ---------------------------------------------------------------------------
// k_gl: fused pose-GEMM + LBS, 32v x 32n tiles, grid (216,16). Wave w:
// wg=w&1 picks 16-n group, wc=w>>1 picks 48-col half (3 ct x 7 kk MFMAs).
// Stage 2: wave w owns 8 n-rows x 32 verts via 2 register w16 frags
// (operand-swapped T-MFMA: lane (m,q) gets T[q][0..3] of vertex g*16+m).
// 2 barriers total.
__global__ __launch_bounds__(256) void k_gl(const unsigned short* __restrict__ apf,
                                            const unsigned short* __restrict__ bp,
                                            const float* __restrict__ vt,
                                            const float* __restrict__ ws,
                                            const _Float16* __restrict__ w16,
                                            const _Float16* __restrict__ an16,
                                            const float* __restrict__ trans,
                                            _Float16* __restrict__ vb) {
    int tid = threadIdx.x;
    int lane = tid & 63, w = tid >> 6;
    int m = lane & 15, q = lane >> 4;
    int cb = blockIdx.x;                 // 0..215  (32-v tile)
    int nb = blockIdx.y;                 // 0..15   (32-n tile)
    int wg = w & 1;                      // n 16-group within tile
    int wc = w >> 1;                     // col 48-half

    // posed verts [n(32)][v(33 pad)][c(4)] fp16 = 8.25 KB; row stride 264 B.
    __shared__ __align__(16) _Float16 sm[32][33][4];
    __shared__ float svt[96];
    __shared__ float ssc[32];
    __shared__ float strans[96];
    if (tid < 96) {
        int col = cb * 96 + tid;
        svt[tid] = (col < V3) ? vt[col] : 0.f;
        strans[tid] = trans[nb * 96 + tid];
    }
    if (tid < 32) ssc[tid] = ws[SCALE_OFF + nb * 32 + tid];

    // ---- stage 1: pose GEMM (16 n x 48 cols per wave)
    const unsigned short* abase = apf + (size_t)(nb * 2 + wg) * 7 * 512 + lane * 8;
    const unsigned short* bbase = bp + (size_t)(cb * 6 + wc * 3) * 7 * 512 + lane * 8;

    f32x4 acc[3];
#pragma unroll
    for (int ct = 0; ct < 3; ++ct) acc[ct] = (f32x4){0.f, 0.f, 0.f, 0.f};

#pragma unroll
    for (int kk = 0; kk < 7; ++kk) {
        s16x8 a = *reinterpret_cast<const s16x8*>(abase + kk * 512);
#pragma unroll
        for (int ct = 0; ct < 3; ++ct) {
            s16x8 bfr = *reinterpret_cast<const s16x8*>(bbase + (ct * 7 + kk) * 512);
            acc[ct] = __builtin_amdgcn_mfma_f32_16x16x32_bf16(a, bfr, acc[ct], 0, 0, 0);
        }
    }

    // w16 fragments for the 2 vertex groups (independent of acc; issue early)
    h16x8 wf[2];
#pragma unroll
    for (int g = 0; g < 2; ++g)
        wf[g] = *reinterpret_cast<const h16x8*>(
            &w16[(size_t)(cb * 32 + g * 16 + m) * 32 + q * 8]);

    __syncthreads();          // svt/ssc/strans ready
#pragma unroll
    for (int ct = 0; ct < 3; ++ct) {
        int col_loc = (wc * 3 + ct) * 16 + m;
        int v_loc = col_loc / 3;
        int c = col_loc - 3 * v_loc;
        float vtc = svt[col_loc];
#pragma unroll
        for (int r = 0; r < 4; ++r) {
            int n_loc = wg * 16 + q * 4 + r;
            sm[n_loc][v_loc][c] = (_Float16)(acc[ct][r] + ssc[n_loc] * vtc);
        }
    }

    // ---- stage 2: LBS, wave w owns n-rows [w*8, w*8+8) x all 32 verts
    __syncthreads();                          // sm complete

    const _Float16* anb = an16 + (size_t)(nb * 32 + w * 8) * 512 + m * 32 + q * 8;
    _Float16* vbase = vb + (size_t)(nb * 32 + w * 8) * 3 * VP2 + (size_t)q * VP2
                      + (size_t)cb * 32;
#pragma unroll
    for (int half = 0; half < 2; ++half) {
        h16x8 bf8[4];
#pragma unroll
        for (int i = 0; i < 4; ++i)
            bf8[i] = *reinterpret_cast<const h16x8*>(anb + (size_t)(half * 4 + i) * 512);
#pragma unroll
        for (int i = 0; i < 4; ++i) {
            int nl = w * 8 + half * 4 + i;
            f32x4 at[2];
#pragma unroll
            for (int g = 0; g < 2; ++g) {
                f32x4 z = (f32x4){0.f, 0.f, 0.f, 0.f};
                at[g] = __builtin_amdgcn_mfma_f32_16x16x32_f16(bf8[i], wf[g], z, 0, 0, 0);
            }
            if (q < 3) {
                float tr = strans[nl * 3 + q];
#pragma unroll
                for (int g = 0; g < 2; ++g) {
                    int vl = g * 16 + m;
                    h16x4 p = *reinterpret_cast<const h16x4*>(&sm[nl][vl][0]);
                    float r = at[g][0] * (float)p[0] + at[g][1] * (float)p[1]
                            + at[g][2] * (float)p[2] + at[g][3] + tr;
                    vbase[(size_t)(half * 4 + i) * 3 * VP2 + vl] = (_Float16)r;
                }
            }
        }
    }
}

// ---------------------------------------------------------------------------
// k_regm v5: grid (96 nc-tiles x 6 v-splits), 4 waves, 9 K-steps each.
// rb now in A-fragment layout: each A-load is a contiguous 1KB wave-load.
// LDS combine across 4 waves, atomicAdd partials.
__global__ __launch_bounds__(256) void k_regm(const _Float16* __restrict__ rb,
                                              const _Float16* __restrict__ vb,
                                              float* __restrict__ out) {
    int tid = threadIdx.x;
    int lane = tid & 63, w = tid >> 6;
    int m = lane & 15, q = lane >> 4;
    int nct = blockIdx.x;                    // 0..95
    int split = blockIdx.y;                  // 0..5

    const _Float16* brow = vb + (size_t)(nct * 16 + m) * VP2 + q * 8;
    const _Float16* abase = rb + (size_t)(q * 16 + m) * 8;
    int vstart = (split * 4 + w) * 288;      // 9 steps of 32 per wave
    int stepBase = (split * 4 + w) * 9;

    f32x4 acc[6];
#pragma unroll
    for (int kt = 0; kt < 6; ++kt) acc[kt] = (f32x4){0.f, 0.f, 0.f, 0.f};

#pragma unroll
    for (int s = 0; s < 9; ++s) {
        int off = vstart + s * 32;
        h16x8 b = *reinterpret_cast<const h16x8*>(brow + off);
#pragma unroll
        for (int kt = 0; kt < 6; ++kt) {
            h16x8 a = *reinterpret_cast<const h16x8*>(
                abase + ((size_t)(kt * 216 + stepBase + s) << 9));
            acc[kt] = __builtin_amdgcn_mfma_f32_16x16x32_f16(a, b, acc[kt], 0, 0, 0);
        }
    }
    __shared__ float sm[4][6][256];          // 24 KB
#pragma unroll
    for (int kt = 0; kt < 6; ++kt)
#pragma unroll
        for (int r = 0; r < 4; ++r)
            sm[w][kt][(q * 4 + r) * 16 + m] = acc[kt][r];
    __syncthreads();
    for (int e = tid; e < 6 * 256; e += 256) {
        int kt = e >> 8, i = e & 255;
        float s = sm[0][kt][i] + sm[1][kt][i] + sm[2][kt][i] + sm[3][kt][i];
        int k = kt * 16 + (i >> 4);
        int nc = nct * 16 + (i & 15);
        if (k < NK) {
            int n = nc / 3, c = nc - n * 3;
            atomicAdd(&out[(size_t)n * (NK * 3) + k * 3 + c], s);
        }
    }
}

// ---------------------------------------------------------------------------
extern "C" void kernel_launch(void* const* d_in, const int* in_sizes, int n_in,
                              void* d_out, int out_size, void* d_ws, size_t ws_size,
                              hipStream_t stream) {
    const float* pose  = (const float*)d_in[0];
    const float* betas = (const float*)d_in[1];
    const float* trans = (const float*)d_in[2];
    const float* vt    = (const float*)d_in[3];
    const float* sd    = (const float*)d_in[4];
    const float* jreg  = (const float*)d_in[5];
    const float* pdirs = (const float*)d_in[6];
    const float* lbsw  = (const float*)d_in[7];
    const float* b25   = (const float*)d_in[8];
    const float* face  = (const float*)d_in[9];
    float* ws  = (float*)d_ws;
    float* out = (float*)d_out;
    unsigned short* bf  = (unsigned short*)(ws + BF_OFF);
    unsigned short* apf = bf + APF_U;
    unsigned short* bp  = bf + BP_U;
    _Float16* rb  = (_Float16*)(bf + RB_U);
    _Float16* vb  = (_Float16*)(bf + VB_U);
    _Float16* w16 = (_Float16*)(ws + WT_OFF);
    _Float16* an16 = (_Float16*)(ws + AN_OFF);

    hipMemsetAsync(d_out, 0, (size_t)out_size * sizeof(float), stream);

    k_static<<<NB_STATIC, 256, 0, stream>>>(pdirs, sd, jreg, vt, lbsw, b25, face,
                                            bp, rb, w16, ws);
    k_head  <<<N, 64, 0, stream>>>(pose, betas, vt, sd, ws, apf, an16);
    k_gl    <<<dim3(216, 16), 256, 0, stream>>>(apf, bp, vt, ws, w16, an16, trans, vb);
    k_regm  <<<dim3(96, 6), 256, 0, stream>>>(rb, vb, out);
}